// Round 1
// baseline (543.758 us; speedup 1.0000x reference)
//
#include <hip/hip_runtime.h>
#include <math.h>

#define HW2   62
#define NA    9
#define NANCH 34596   // 62*62*9
#define NPIX  3844    // 62*62
#define NBAT  16
#define NGT   8
#define FEATC 256
#define NOUT  45      // 9 cls + 36 box channels

// ---------- shared device helpers ----------

// Anchor geometry (exact in fp32; matches _anchor_base()).
// a = r*3 + s_idx, ws = s*r, hs = s;  r in {0.5,1,2}, s in {2,4,6}
__device__ __forceinline__ void anchor4(int i, int j, int a,
                                        float& x1, float& y1, float& x2, float& y2) {
    int am = a % 3, ad = a / 3;
    float h = 2.f * (float)(am + 1);              // 2,4,6
    float w = h * 0.5f * (float)(1 << ad);        // h*{0.5,1,2}
    float cx = (float)i + 0.5f, cy = (float)j + 0.5f;
    x1 = fminf(fmaxf(cx - 0.5f * w, 0.f), 62.f);
    x2 = fminf(fmaxf(cx + 0.5f * w, 0.f), 62.f);
    y1 = fminf(fmaxf(cy - 0.5f * h, 0.f), 62.f);
    y2 = fminf(fmaxf(cy + 0.5f * h, 0.f), 62.f);
}

// IoU with contraction-blocked IEEE ops so every call site produces
// bitwise-identical values (pos_mask needs exact == against the max).
__device__ __forceinline__ float iou_fn(float ax1, float ay1, float ax2, float ay2,
                                        float gx1, float gy1, float gx2, float gy2) {
    float area_a = __fmul_rn(__fsub_rn(ax2, ax1), __fsub_rn(ay2, ay1));
    float area_g = __fmul_rn(__fsub_rn(gx2, gx1), __fsub_rn(gy2, gy1));
    float ix1 = fmaxf(ax1, gx1), iy1 = fmaxf(ay1, gy1);
    float ix2 = fminf(ax2, gx2), iy2 = fminf(ay2, gy2);
    float iw = fmaxf(__fsub_rn(ix2, ix1), 0.f);
    float ih = fmaxf(__fsub_rn(iy2, iy1), 0.f);
    float inter = __fmul_rn(iw, ih);
    float uni = __fsub_rn(__fadd_rn(area_a, area_g), inter);
    return inter / fmaxf(uni, 1e-9f);
}

__device__ __forceinline__ float softplus_f(float x) {
    return fmaxf(x, 0.f) + log1pf(expf(-fabsf(x)));
}

__device__ __forceinline__ float sl1_f(float d) {
    float ad = fabsf(d);
    return (ad < 1.f) ? 0.5f * d * d : (ad - 0.5f);
}

// ---------- Kernel A: fold 1x1 heads into the 3x3 conv ----------
// effw[(c*9+tap)*45 + o] = sum_mid w2[o][mid] * conv_w[mid][c][tap]
__global__ void fold_w(const float* __restrict__ conv_w, const float* __restrict__ conv_b,
                       const float* __restrict__ cls_w,  const float* __restrict__ cls_b,
                       const float* __restrict__ box_w,  const float* __restrict__ box_b,
                       float* __restrict__ effw, float* __restrict__ effb) {
    int o = blockIdx.x;
    const float* w2 = (o < 9) ? (cls_w + o * FEATC) : (box_w + (o - 9) * FEATC);
    int tid = threadIdx.x;
    for (int idx = tid; idx < 2304; idx += 256) {
        float acc = 0.f;
#pragma unroll 8
        for (int mid = 0; mid < FEATC; ++mid)
            acc = fmaf(w2[mid], conv_w[mid * 2304 + idx], acc);
        effw[idx * NOUT + o] = acc;
    }
    if (tid == 0) {
        float acc = (o < 9) ? cls_b[o] : box_b[o - 9];
        for (int mid = 0; mid < FEATC; ++mid) acc = fmaf(w2[mid], conv_b[mid], acc);
        effb[o] = acc;
    }
}

// ---------- Kernel C1: max IoU per (batch, gt) over all anchors ----------
__global__ void gt_max_iou(const float* __restrict__ gtb, float* __restrict__ maxiou) {
    int bg = blockIdx.x;
    int b = bg >> 3, g = bg & 7;
    const float* p = gtb + (b * NGT + g) * 4;
    float gx1 = p[0] * 0.125f, gy1 = p[1] * 0.125f;
    float gx2 = p[2] * 0.125f, gy2 = p[3] * 0.125f;
    float m = 0.f;
    for (int n = threadIdx.x; n < NANCH; n += 256) {
        int i = n / 558; int r = n - i * 558; int j = r / 9; int a = r - j * 9;
        float ax1, ay1, ax2, ay2;
        anchor4(i, j, a, ax1, ay1, ax2, ay2);
        m = fmaxf(m, iou_fn(ax1, ay1, ax2, ay2, gx1, gy1, gx2, gy2));
    }
    __shared__ float red[256];
    red[threadIdx.x] = m;
    __syncthreads();
    for (int s = 128; s > 0; s >>= 1) {
        if (threadIdx.x < s) red[threadIdx.x] = fmaxf(red[threadIdx.x], red[threadIdx.x + s]);
        __syncthreads();
    }
    if (threadIdx.x == 0) maxiou[bg] = red[0];
}

// ---------- Kernel B1: fp32 3x3 conv (folded weights), channel-group partials ----------
// grid = (16 tiles, ng groups, 16 batch), block = 256 (16x16 output pixels)
// partial[((grp*NBAT + b)*NPIX + pix)*45 + o]
__global__ void conv_part(const float* __restrict__ feat, const float* __restrict__ effw,
                          const float* __restrict__ effb, float* __restrict__ partial, int ng) {
    int tile = blockIdx.x, grp = blockIdx.y, b = blockIdx.z;
    int tY = tile >> 2, tX = tile & 3;
    int tid = threadIdx.x;
    int ty = tid >> 4, tx = tid & 15;
    int oy = tY * 16 + ty, ox = tX * 16 + tx;
    bool valid = (oy < HW2) && (ox < HW2);
    int cpg = FEATC / ng;
    int c_base = grp * cpg;

    float acc[NOUT];
#pragma unroll
    for (int o = 0; o < NOUT; ++o) acc[o] = (grp == 0) ? effb[o] : 0.f;

    __shared__ float tile_s[8][18][18];
    int nchunk = cpg >> 3;
    for (int cc = 0; cc < nchunk; ++cc) {
        int c0 = c_base + cc * 8;
        __syncthreads();
        for (int idx = tid; idx < 8 * 324; idx += 256) {
            int c = idx / 324; int rem = idx - c * 324;
            int iy = rem / 18; int ix = rem - iy * 18;
            int gy = tY * 16 + iy, gx = tX * 16 + ix;
            float v = 0.f;
            if (gy < 64 && gx < 64)
                v = feat[(((size_t)b * FEATC + (c0 + c)) * 64 + gy) * 64 + gx];
            tile_s[c][iy][ix] = v;
        }
        __syncthreads();
#pragma unroll
        for (int c = 0; c < 8; ++c) {
            float v[9];
#pragma unroll
            for (int dy = 0; dy < 3; ++dy)
#pragma unroll
                for (int dx = 0; dx < 3; ++dx)
                    v[dy * 3 + dx] = tile_s[c][ty + dy][tx + dx];
            const float* wp = effw + (size_t)(c0 + c) * 9 * NOUT;  // block-uniform -> s_load
#pragma unroll
            for (int t = 0; t < 9; ++t) {
                float vv = v[t];
#pragma unroll
                for (int o = 0; o < NOUT; ++o)
                    acc[o] = fmaf(vv, wp[t * NOUT + o], acc[o]);
            }
        }
    }
    if (valid) {
        size_t base = (((size_t)grp * NBAT + b) * NPIX + (oy * HW2 + ox)) * NOUT;
#pragma unroll
        for (int o = 0; o < NOUT; ++o) partial[base + o] = acc[o];
    }
}

// ---------- Kernel C2: fused epilogue (proposals, masks, gt_cls, loss partials) ----------
__global__ void epilogue(const float* __restrict__ partial, const float* __restrict__ gtb,
                         const int* __restrict__ gtc, const float* __restrict__ maxiou,
                         float* __restrict__ outp, float* __restrict__ blksums,
                         int ng, int nblk) {
    int b = blockIdx.y;
    int n = blockIdx.x * 256 + threadIdx.x;
    bool act = n < NANCH;
    float s_pos = 0.f, s_neg = 0.f, s_pl = 0.f, s_nl = 0.f, s_reg = 0.f;

    float* out_prop = outp + 2;
    float* out_mask = out_prop + (size_t)NBAT * NANCH * 4;
    float* out_gtc  = out_mask + (size_t)NBAT * NANCH * 8;

    if (act) {
        int i = n / 558; int r = n - i * 558; int j = r / 9; int a = r - j * 9;
        int pix = i * HW2 + j;
        size_t base = ((size_t)b * NPIX + pix) * NOUT;
        size_t gstr = (size_t)NBAT * NPIX * NOUT;
        float cls = 0.f, p0 = 0.f, p1 = 0.f, p2 = 0.f, p3 = 0.f;
        for (int g = 0; g < ng; ++g) {
            const float* pp = partial + (size_t)g * gstr + base;
            cls += pp[a];
            p0 += pp[9 + 4 * a]; p1 += pp[10 + 4 * a];
            p2 += pp[11 + 4 * a]; p3 += pp[12 + 4 * a];
        }
        float ax1, ay1, ax2, ay2;
        anchor4(i, j, a, ax1, ay1, ax2, ay2);
        float aw = ax2 - ax1, ah = ay2 - ay1;
        float acx = 0.5f * (ax1 + ax2), acy = 0.5f * (ay1 + ay2);

        // proposals
        const float ps = 64.f / 62.f;
        float pcx = acx + p0 * aw, pcy = acy + p1 * ah;
        float pw = aw * expf(p2), ph = ah * expf(p3);
        size_t pb = ((size_t)b * NANCH + n) * 4;
        out_prop[pb + 0] = (pcx - 0.5f * pw) * ps;
        out_prop[pb + 1] = (pcy - 0.5f * ph) * ps;
        out_prop[pb + 2] = (pcx + 0.5f * pw) * ps;
        out_prop[pb + 3] = (pcy + 0.5f * ph) * ps;

        float law = logf(aw), lah = logf(ah);
        float posf_tot = 0.f, negf_tot = 0.f;
        float best_iou = -1.f; int best_g = 0;
        size_t mb = ((size_t)b * NANCH + n) * 8;
#pragma unroll
        for (int g = 0; g < NGT; ++g) {
            const float* gp = gtb + (b * NGT + g) * 4;
            float gx1 = gp[0] * 0.125f, gy1 = gp[1] * 0.125f;
            float gx2 = gp[2] * 0.125f, gy2 = gp[3] * 0.125f;
            float iou = iou_fn(ax1, ay1, ax2, ay2, gx1, gy1, gx2, gy2);
            float mpg = maxiou[b * NGT + g];
            bool pm = ((iou == mpg) && (mpg > 0.f)) || (iou > 0.7f);
            float pf = pm ? 1.f : 0.f;
            float nf = (iou < 0.3f) ? 1.f : 0.f;
            out_mask[mb + g] = pf;
            posf_tot += pf; negf_tot += nf;
            if (iou > best_iou) { best_iou = iou; best_g = g; }   // first-max-wins
            if (pm) {
                float gw = gx2 - gx1, gh = gy2 - gy1;
                float gcx = 0.5f * (gx1 + gx2), gcy = 0.5f * (gy1 + gy2);
                float tx_ = (gcx - acx) / aw, ty_ = (gcy - acy) / ah;
                float tw_ = logf(gw) - law, th_ = logf(gh) - lah;
                float d0 = p0 - tx_, d1 = p1 - ty_, d2 = p2 - tw_, d3 = p3 - th_;
                s_reg += sl1_f(d0) + sl1_f(d1) + sl1_f(d2) + sl1_f(d3);
            }
        }
        s_pos = posf_tot; s_neg = negf_tot;
        s_pl = softplus_f(-cls) * posf_tot;
        s_nl = softplus_f(cls) * negf_tot;
        out_gtc[(size_t)b * NANCH + n] = (float)gtc[b * NGT + best_g];
    }

    // deterministic per-block tree reduction of the 5 loss partials
    __shared__ float red[256];
    int tid = threadIdx.x;
    int blk = blockIdx.y * gridDim.x + blockIdx.x;
    float vals[5] = {s_pos, s_neg, s_pl, s_nl, s_reg};
#pragma unroll
    for (int s = 0; s < 5; ++s) {
        red[tid] = vals[s];
        __syncthreads();
        for (int st = 128; st > 0; st >>= 1) {
            if (tid < st) red[tid] += red[tid + st];
            __syncthreads();
        }
        if (tid == 0) blksums[(size_t)s * nblk + blk] = red[0];
        __syncthreads();
    }
}

// ---------- Kernel D: final fixed-order reduction + losses ----------
__global__ void finalize(const float* __restrict__ blksums, int nblk, float* __restrict__ outp) {
    __shared__ float red[256];
    __shared__ float tot[5];
    int tid = threadIdx.x;
#pragma unroll
    for (int s = 0; s < 5; ++s) {
        float acc = 0.f;
        for (int i = tid; i < nblk; i += 256) acc += blksums[(size_t)s * nblk + i];
        red[tid] = acc;
        __syncthreads();
        for (int st = 128; st > 0; st >>= 1) {
            if (tid < st) red[tid] += red[tid + st];
            __syncthreads();
        }
        if (tid == 0) tot[s] = red[0];
        __syncthreads();
    }
    if (tid == 0) {
        float np_ = fmaxf(tot[0], 1.f), nn_ = fmaxf(tot[1], 1.f);
        outp[0] = 0.5f * (tot[2] / np_ + tot[3] / nn_);  // cls_loss
        outp[1] = tot[4] / (np_ * 4.f);                  // reg_loss
    }
}

extern "C" void kernel_launch(void* const* d_in, const int* in_sizes, int n_in,
                              void* d_out, int out_size, void* d_ws, size_t ws_size,
                              hipStream_t stream) {
    (void)in_sizes; (void)n_in; (void)out_size;
    const float* feat   = (const float*)d_in[0];
    const float* gtb    = (const float*)d_in[1];
    const int*   gtc    = (const int*)d_in[2];
    const float* conv_w = (const float*)d_in[3];
    const float* conv_b = (const float*)d_in[4];
    const float* cls_w  = (const float*)d_in[5];
    const float* cls_b  = (const float*)d_in[6];
    const float* box_w  = (const float*)d_in[7];
    const float* box_b  = (const float*)d_in[8];
    float* outp = (float*)d_out;
    float* ws   = (float*)d_ws;

    const int nblk = 136 * NBAT;  // epilogue blocks
    size_t avail = ws_size / 4;   // floats
    int ng = 4;
    while (ng > 1 &&
           (size_t)103680 + 64 + 128 + (size_t)ng * NBAT * NPIX * NOUT + 5 * (size_t)nblk > avail)
        ng >>= 1;

    float* effw    = ws;
    float* effb    = ws + 103680;
    float* maxiou  = effb + 64;
    float* partial = maxiou + 128;
    float* blksums = partial + (size_t)ng * NBAT * NPIX * NOUT;

    fold_w<<<45, 256, 0, stream>>>(conv_w, conv_b, cls_w, cls_b, box_w, box_b, effw, effb);
    gt_max_iou<<<128, 256, 0, stream>>>(gtb, maxiou);
    conv_part<<<dim3(16, ng, 16), 256, 0, stream>>>(feat, effw, effb, partial, ng);
    epilogue<<<dim3(136, NBAT), 256, 0, stream>>>(partial, gtb, gtc, maxiou, outp, blksums, ng, nblk);
    finalize<<<1, 256, 0, stream>>>(blksums, nblk, outp);
}

// Round 2
// 157.658 us; speedup vs baseline: 3.4490x; 3.4490x over previous
//
#include <hip/hip_runtime.h>
#include <math.h>

#define HW2   62
#define NANCH 34596   // 62*62*9
#define NBAT  16
#define NGT   8
#define FEATC 256
#define NOUT  45      // 9 cls + 36 box channels

typedef short bf16x8 __attribute__((ext_vector_type(8)));
typedef float f32x4  __attribute__((ext_vector_type(4)));

// fp32 -> bf16 round-to-nearest-even
__device__ __forceinline__ unsigned short f2bf(float f) {
    unsigned int u = __float_as_uint(f);
    u = u + 0x7FFFu + ((u >> 16) & 1u);
    return (unsigned short)(u >> 16);
}

// ---------- shared device helpers (bitwise identical to the passing R0) ----------

__device__ __forceinline__ void anchor4(int i, int j, int a,
                                        float& x1, float& y1, float& x2, float& y2) {
    int am = a % 3, ad = a / 3;
    float h = 2.f * (float)(am + 1);              // 2,4,6
    float w = h * 0.5f * (float)(1 << ad);        // h*{0.5,1,2}
    float cx = (float)i + 0.5f, cy = (float)j + 0.5f;
    x1 = fminf(fmaxf(cx - 0.5f * w, 0.f), 62.f);
    x2 = fminf(fmaxf(cx + 0.5f * w, 0.f), 62.f);
    y1 = fminf(fmaxf(cy - 0.5f * h, 0.f), 62.f);
    y2 = fminf(fmaxf(cy + 0.5f * h, 0.f), 62.f);
}

__device__ __forceinline__ float iou_fn(float ax1, float ay1, float ax2, float ay2,
                                        float gx1, float gy1, float gx2, float gy2) {
    float area_a = __fmul_rn(__fsub_rn(ax2, ax1), __fsub_rn(ay2, ay1));
    float area_g = __fmul_rn(__fsub_rn(gx2, gx1), __fsub_rn(gy2, gy1));
    float ix1 = fmaxf(ax1, gx1), iy1 = fmaxf(ay1, gy1);
    float ix2 = fminf(ax2, gx2), iy2 = fminf(ay2, gy2);
    float iw = fmaxf(__fsub_rn(ix2, ix1), 0.f);
    float ih = fmaxf(__fsub_rn(iy2, iy1), 0.f);
    float inter = __fmul_rn(iw, ih);
    float uni = __fsub_rn(__fadd_rn(area_a, area_g), inter);
    return inter / fmaxf(uni, 1e-9f);
}

__device__ __forceinline__ float softplus_f(float x) {
    return fmaxf(x, 0.f) + log1pf(expf(-fabsf(x)));
}

__device__ __forceinline__ float sl1_f(float d) {
    float ad = fabsf(d);
    return (ad < 1.f) ? 0.5f * d * d : (ad - 0.5f);
}

// ---------- Kernel A1: fold partials (mid split x4) ----------
// partial[g][idx][45], idx = c*9+tap
__global__ void fold_part(const float* __restrict__ conv_w,
                          const float* __restrict__ cls_w,
                          const float* __restrict__ box_w,
                          float* __restrict__ partial) {
    int idx = blockIdx.x * 256 + threadIdx.x;   // 0..2303
    int g = blockIdx.y;                          // 0..3
    float acc[NOUT];
#pragma unroll
    for (int o = 0; o < NOUT; ++o) acc[o] = 0.f;
    for (int mid = g * 64; mid < g * 64 + 64; ++mid) {
        float cw = conv_w[mid * 2304 + idx];      // coalesced
#pragma unroll
        for (int o = 0; o < NOUT; ++o) {          // uniform -> s_load
            float wv = (o < 9) ? cls_w[o * FEATC + mid] : box_w[(o - 9) * FEATC + mid];
            acc[o] = fmaf(cw, wv, acc[o]);
        }
    }
    float* p = partial + (size_t)(g * 2304 + idx) * NOUT;
#pragma unroll
    for (int o = 0; o < NOUT; ++o) p[o] = acc[o];
}

// ---------- Kernel A2: combine partials -> B fragments (bf16) + effb ----------
// Bfrag element (cc,tap,kk,nf,lane,j) = effw(c = cc*64+kk*32+8*(lane>>4)+j, tap, o = nf*16+(lane&15))
__global__ void fold_combine(const float* __restrict__ partial,
                             const float* __restrict__ conv_b,
                             const float* __restrict__ cls_b,
                             const float* __restrict__ box_b,
                             const float* __restrict__ cls_w,
                             const float* __restrict__ box_w,
                             unsigned short* __restrict__ Bfrag,
                             float* __restrict__ effb) {
    int i = blockIdx.x * 256 + threadIdx.x;   // < 110592 = 2304*48
    int o = i % 48, idx = i / 48;
    int c = idx / 9, tap = idx - c * 9;
    float s = 0.f;
    if (o < NOUT) {
#pragma unroll
        for (int g = 0; g < 4; ++g) s += partial[(size_t)(g * 2304 + idx) * NOUT + o];
    }
    int cc = c >> 6, kk = (c >> 5) & 1, lh = (c >> 3) & 3, j = c & 7;
    int lane = (lh << 4) | (o & 15), nf = o >> 4;
    Bfrag[((size_t)((((cc * 9 + tap) * 2 + kk) * 3 + nf) * 64 + lane)) * 8 + j] = f2bf(s);

    if (blockIdx.x == 0 && threadIdx.x < 48) {
        int t = threadIdx.x;
        float bv = 0.f;
        if (t < NOUT) {
            bv = (t < 9) ? cls_b[t] : box_b[t - 9];
            const float* w2 = (t < 9) ? (cls_w + t * FEATC) : (box_w + (t - 9) * FEATC);
            for (int mid = 0; mid < FEATC; ++mid) bv = fmaf(w2[mid], conv_b[mid], bv);
        }
        effb[t] = bv;
    }
}

// ---------- Kernel C1: max IoU per (batch, gt) over all anchors ----------
__global__ void gt_max_iou(const float* __restrict__ gtb, float* __restrict__ maxiou) {
    int bg = blockIdx.x;
    int b = bg >> 3, g = bg & 7;
    const float* p = gtb + (b * NGT + g) * 4;
    float gx1 = p[0] * 0.125f, gy1 = p[1] * 0.125f;
    float gx2 = p[2] * 0.125f, gy2 = p[3] * 0.125f;
    float m = 0.f;
    for (int n = threadIdx.x; n < NANCH; n += 256) {
        int i = n / 558; int r = n - i * 558; int j = r / 9; int a = r - j * 9;
        float ax1, ay1, ax2, ay2;
        anchor4(i, j, a, ax1, ay1, ax2, ay2);
        m = fmaxf(m, iou_fn(ax1, ay1, ax2, ay2, gx1, gy1, gx2, gy2));
    }
    __shared__ float red[256];
    red[threadIdx.x] = m;
    __syncthreads();
    for (int s = 128; s > 0; s >>= 1) {
        if (threadIdx.x < s) red[threadIdx.x] = fmaxf(red[threadIdx.x], red[threadIdx.x + s]);
        __syncthreads();
    }
    if (threadIdx.x == 0) maxiou[bg] = red[0];
}

// ---------- Kernel B: MFMA implicit-GEMM conv + fused epilogue ----------
// grid = (32 spatial tiles [8 tY x 4 tX], 16 batch), block = 256 (4 waves)
// tile = 8 rows (oy) x 16 cols (ox); wave w owns rows 2w..2w+1 (2 m-frags x 3 n-frags)
__launch_bounds__(256, 2)
__global__ void conv_fused(const float* __restrict__ feat,
                           const unsigned short* __restrict__ Bfrag,
                           const float* __restrict__ effb,
                           const float* __restrict__ gtb,
                           const int* __restrict__ gtc,
                           const float* __restrict__ maxiou,
                           float* __restrict__ outp,
                           float* __restrict__ blksums) {
    __shared__ __align__(16) unsigned short ldsA[2][180 * 64];  // [pix 10x18][64 ch] bf16, XOR-swizzled
    __shared__ float Cs[128][48];
    __shared__ float gshr[40];
    __shared__ float red[256];

    const int t = threadIdx.x, l = t & 63, w = t >> 6;
    const int bx = blockIdx.x, b = blockIdx.y;
    const int tY = bx >> 2, tX = bx & 3;
    const int l15 = l & 15, lq = l >> 4;

    // stage gt boxes (scaled) + per-gt max iou into LDS
    if (t < 32) gshr[t] = gtb[b * 32 + t] * 0.125f;
    else if (t < 40) gshr[t] = maxiou[b * 8 + (t - 32)];

    // accumulators init = folded bias (per output col)
    f32x4 acc[2][3];
#pragma unroll
    for (int nf = 0; nf < 3; ++nf) {
        float bv = effb[nf * 16 + l15];
#pragma unroll
        for (int mf = 0; mf < 2; ++mf)
#pragma unroll
            for (int r = 0; r < 4; ++r) acc[mf][nf][r] = bv;
    }

    float vr[6][8];  // staged regs: 6 (pix-group, ch-group) pairs x 8 channels

    auto stage_load = [&](int cc) {
#pragma unroll
        for (int q = 0; q < 6; ++q) {
            int pi = w * 6 + q;                 // 0..23
            int pg = pi >> 3, cg = pi & 7;
            int pix = pg * 64 + l;              // 0..191 (need <180)
            int iy = pix / 18, ix = pix - iy * 18;
            int gy = tY * 8 + iy, gx = tX * 16 + ix;
            bool ok = (pix < 180) && (gy < 64) && (gx < 64);
            const float* src = feat + (((size_t)b * FEATC + cc * 64 + cg * 8) * 64 + gy) * 64 + gx;
#pragma unroll
            for (int k = 0; k < 8; ++k)
                vr[q][k] = ok ? src[(size_t)k * 4096] : 0.f;
        }
    };
    auto stage_write = [&](int bb) {
        char* base = (char*)&ldsA[bb][0];
#pragma unroll
        for (int q = 0; q < 6; ++q) {
            int pi = w * 6 + q;
            int pg = pi >> 3, cg = pi & 7;
            int pix = pg * 64 + l;
            if (pix < 180) {
                bf16x8 v;
#pragma unroll
                for (int k = 0; k < 8; ++k) v[k] = (short)f2bf(vr[q][k]);
                int byte = (pix * 128 + cg * 16) ^ ((pix & 7) << 4);
                *reinterpret_cast<bf16x8*>(base + byte) = v;
            }
        }
    };
    auto compute = [&](int cc, int bb) {
        const bf16x8* Bp = reinterpret_cast<const bf16x8*>(Bfrag);
        const char* base = (const char*)&ldsA[bb][0];
#pragma unroll
        for (int dy = 0; dy < 3; ++dy)
#pragma unroll
            for (int dx = 0; dx < 3; ++dx)
#pragma unroll
                for (int kk = 0; kk < 2; ++kk) {
                    int tap = dy * 3 + dx;
                    bf16x8 bfr[3];
#pragma unroll
                    for (int nf = 0; nf < 3; ++nf)
                        bfr[nf] = Bp[(((cc * 9 + tap) * 2 + kk) * 3 + nf) * 64 + l];
                    bf16x8 afr[2];
#pragma unroll
                    for (int mf = 0; mf < 2; ++mf) {
                        int pix = (w * 2 + mf + dy) * 18 + l15 + dx;
                        int byte = (pix * 128 + kk * 64 + (lq << 4)) ^ ((pix & 7) << 4);
                        afr[mf] = *reinterpret_cast<const bf16x8*>(base + byte);
                    }
#pragma unroll
                    for (int mf = 0; mf < 2; ++mf)
#pragma unroll
                        for (int nf = 0; nf < 3; ++nf)
                            acc[mf][nf] = __builtin_amdgcn_mfma_f32_16x16x32_bf16(
                                afr[mf], bfr[nf], acc[mf][nf], 0, 0, 0);
                }
    };

    // K-loop over 4 channel chunks, double-buffered (issue-early / write-late)
    stage_load(0);
    stage_write(0);
    __syncthreads();
    for (int cc = 0; cc < 4; ++cc) {
        if (cc < 3) stage_load(cc + 1);      // global loads in flight during MFMA
        compute(cc, cc & 1);
        if (cc < 3) stage_write((cc + 1) & 1);  // other buffer: safe during peers' compute
        __syncthreads();
    }

    // C fragments -> LDS (row = l&15 is the x-pixel; C rows (lq*4+r) are ox offsets)
#pragma unroll
    for (int mf = 0; mf < 2; ++mf) {
        int py = w * 2 + mf;
#pragma unroll
        for (int nf = 0; nf < 3; ++nf)
#pragma unroll
            for (int r = 0; r < 4; ++r) {
                int px = (lq << 2) + r;
                Cs[py * 16 + px][nf * 16 + l15] = acc[mf][nf][r];
            }
    }
    __syncthreads();

    // ---- fused per-anchor epilogue: 8x16 pixels x 9 anchors = 1152 anchors ----
    float s_pos = 0.f, s_neg = 0.f, s_pl = 0.f, s_nl = 0.f, s_reg = 0.f;
    float* out_prop = outp + 2;
    float* out_mask = out_prop + (size_t)NBAT * NANCH * 4;
    float* out_gtc  = out_mask + (size_t)NBAT * NANCH * 8;

    for (int k = 0; k < 5; ++k) {
        int an = k * 256 + t;
        if (an < 1152) {
            int pixloc = an / 9, a = an - pixloc * 9;
            int py = pixloc >> 4, px = pixloc & 15;
            int oy = tY * 8 + py, ox = tX * 16 + px;
            if (oy < HW2 && ox < HW2) {
                int n = oy * 558 + ox * 9 + a;
                float cls = Cs[pixloc][a];
                float p0 = Cs[pixloc][9 + 4 * a];
                float p1 = Cs[pixloc][10 + 4 * a];
                float p2 = Cs[pixloc][11 + 4 * a];
                float p3 = Cs[pixloc][12 + 4 * a];

                float ax1, ay1, ax2, ay2;
                anchor4(oy, ox, a, ax1, ay1, ax2, ay2);
                float aw = ax2 - ax1, ah = ay2 - ay1;
                float acx = 0.5f * (ax1 + ax2), acy = 0.5f * (ay1 + ay2);

                const float ps = 64.f / 62.f;
                float pcx = acx + p0 * aw, pcy = acy + p1 * ah;
                float pw = aw * expf(p2), ph = ah * expf(p3);
                size_t pb = ((size_t)b * NANCH + n) * 4;
                out_prop[pb + 0] = (pcx - 0.5f * pw) * ps;
                out_prop[pb + 1] = (pcy - 0.5f * ph) * ps;
                out_prop[pb + 2] = (pcx + 0.5f * pw) * ps;
                out_prop[pb + 3] = (pcy + 0.5f * ph) * ps;

                float law = logf(aw), lah = logf(ah);
                float posf_tot = 0.f, negf_tot = 0.f;
                float best_iou = -1.f; int best_g = 0;
                size_t mb = ((size_t)b * NANCH + n) * 8;
#pragma unroll
                for (int g = 0; g < NGT; ++g) {
                    float gx1 = gshr[g * 4 + 0], gy1 = gshr[g * 4 + 1];
                    float gx2 = gshr[g * 4 + 2], gy2 = gshr[g * 4 + 3];
                    float iou = iou_fn(ax1, ay1, ax2, ay2, gx1, gy1, gx2, gy2);
                    float mpg = gshr[32 + g];
                    bool pm = ((iou == mpg) && (mpg > 0.f)) || (iou > 0.7f);
                    float pf = pm ? 1.f : 0.f;
                    float nf = (iou < 0.3f) ? 1.f : 0.f;
                    out_mask[mb + g] = pf;
                    posf_tot += pf; negf_tot += nf;
                    if (iou > best_iou) { best_iou = iou; best_g = g; }  // first-max-wins
                    if (pm) {
                        float gw = gx2 - gx1, gh = gy2 - gy1;
                        float gcx = 0.5f * (gx1 + gx2), gcy = 0.5f * (gy1 + gy2);
                        float tx_ = (gcx - acx) / aw, ty_ = (gcy - acy) / ah;
                        float tw_ = logf(gw) - law, th_ = logf(gh) - lah;
                        float d0 = p0 - tx_, d1 = p1 - ty_, d2 = p2 - tw_, d3 = p3 - th_;
                        s_reg += sl1_f(d0) + sl1_f(d1) + sl1_f(d2) + sl1_f(d3);
                    }
                }
                s_pos += posf_tot; s_neg += negf_tot;
                s_pl += softplus_f(-cls) * posf_tot;
                s_nl += softplus_f(cls) * negf_tot;
                out_gtc[(size_t)b * NANCH + n] = (float)gtc[b * NGT + best_g];
            }
        }
    }

    // deterministic per-block tree reduction of the 5 loss partials
    int blk = b * 32 + bx;   // nblk = 512
    float vals[5] = {s_pos, s_neg, s_pl, s_nl, s_reg};
#pragma unroll
    for (int s = 0; s < 5; ++s) {
        red[t] = vals[s];
        __syncthreads();
        for (int st = 128; st > 0; st >>= 1) {
            if (t < st) red[t] += red[t + st];
            __syncthreads();
        }
        if (t == 0) blksums[(size_t)s * 512 + blk] = red[0];
        __syncthreads();
    }
}

// ---------- Kernel D: final fixed-order reduction + losses ----------
__global__ void finalize(const float* __restrict__ blksums, int nblk, float* __restrict__ outp) {
    __shared__ float red[256];
    __shared__ float tot[5];
    int tid = threadIdx.x;
#pragma unroll
    for (int s = 0; s < 5; ++s) {
        float acc = 0.f;
        for (int i = tid; i < nblk; i += 256) acc += blksums[(size_t)s * nblk + i];
        red[tid] = acc;
        __syncthreads();
        for (int st = 128; st > 0; st >>= 1) {
            if (tid < st) red[tid] += red[tid + st];
            __syncthreads();
        }
        if (tid == 0) tot[s] = red[0];
        __syncthreads();
    }
    if (tid == 0) {
        float np_ = fmaxf(tot[0], 1.f), nn_ = fmaxf(tot[1], 1.f);
        outp[0] = 0.5f * (tot[2] / np_ + tot[3] / nn_);  // cls_loss
        outp[1] = tot[4] / (np_ * 4.f);                  // reg_loss
    }
}

extern "C" void kernel_launch(void* const* d_in, const int* in_sizes, int n_in,
                              void* d_out, int out_size, void* d_ws, size_t ws_size,
                              hipStream_t stream) {
    (void)in_sizes; (void)n_in; (void)out_size; (void)ws_size;
    const float* feat   = (const float*)d_in[0];
    const float* gtb    = (const float*)d_in[1];
    const int*   gtc    = (const int*)d_in[2];
    const float* conv_w = (const float*)d_in[3];
    const float* conv_b = (const float*)d_in[4];
    const float* cls_w  = (const float*)d_in[5];
    const float* cls_b  = (const float*)d_in[6];
    const float* box_w  = (const float*)d_in[7];
    const float* box_b  = (const float*)d_in[8];
    float* outp = (float*)d_out;
    float* ws   = (float*)d_ws;

    // workspace layout (floats): total ~473k floats (1.9 MB)
    unsigned short* Bfrag = (unsigned short*)ws;          // 110592 ushorts = 55296 floats
    float* effb    = ws + 55296;                          // 48 (+pad)
    float* maxiou  = ws + 55360;                          // 128
    float* partial = ws + 55488;                          // 4*2304*45 = 414720
    float* blksums = ws + 470208;                         // 5*512

    fold_part<<<dim3(9, 4), 256, 0, stream>>>(conv_w, cls_w, box_w, partial);
    fold_combine<<<432, 256, 0, stream>>>(partial, conv_b, cls_b, box_b, cls_w, box_w,
                                          Bfrag, effb);
    gt_max_iou<<<128, 256, 0, stream>>>(gtb, maxiou);
    conv_fused<<<dim3(32, NBAT), 256, 0, stream>>>(feat, Bfrag, effb, gtb, gtc, maxiou,
                                                   outp, blksums);
    finalize<<<1, 256, 0, stream>>>(blksums, 512, outp);
}